// Round 2
// baseline (53.730 us; speedup 1.0000x reference)
//
#include <hip/hip_runtime.h>
#include <hip/hip_bf16.h>

// Problem constants
#define PM 8        // groups
#define PK 4096     // codebook entries per group
#define PD 128      // dim
#define PN 8
#define PH 64
#define PW 64

typedef __attribute__((ext_vector_type(8))) short bf16x8;
typedef __attribute__((ext_vector_type(4))) float f32x4;
typedef __attribute__((ext_vector_type(8))) short short8v;

__device__ inline unsigned short f2bf_rne(float f) {
    unsigned int u = __float_as_uint(f);
    unsigned int r = (u + 0x7FFFu + ((u >> 16) & 1u)) >> 16;
    return (unsigned short)r;
}
__device__ inline float bf2f(unsigned short s) {
    return __uint_as_float(((unsigned int)s) << 16);
}

__device__ inline bf16x8 loadcvt8(const float* __restrict__ p) {
    f32x4 x0 = *(const f32x4*)p;
    f32x4 x1 = *(const f32x4*)(p + 4);
    bf16x8 r;
#pragma unroll
    for (int j = 0; j < 4; ++j) {
        r[j]     = (short)f2bf_rne(x0[j]);
        r[j + 4] = (short)f2bf_rne(x1[j]);
    }
    return r;
}

// ---------------------------------------------------------------------------
// Kernel 1: table[m,k,c] = sum_d codebook[m,k,d]*wq[m,c,d] + bq[m,c]  (bf16)
// 8 GEMMs of (4096 x 128) x (128 x 128)^T, K=128, via mfma_f32_16x16x32_bf16.
// Grid: 512 blocks (m = b&7, ktile = (b>>3)*64), 256 threads = 4 waves,
// each wave computes one 16-row k-subtile x 128 c. 2 blocks/CU occupancy.
// ---------------------------------------------------------------------------
__global__ __launch_bounds__(256) void build_table(
        const float* __restrict__ codebook,
        const float* __restrict__ wq,
        const float* __restrict__ bq,
        unsigned short* __restrict__ table) {
    const int b = blockIdx.x;
    const int m = b & 7;
    const int ktile = (b >> 3) * 64;
    const int tid = threadIdx.x;
    const int wv = tid >> 6;       // wave 0..3 -> k-subtile
    const int l  = tid & 63;
    const int lr = l & 15;         // frag row/col index
    const int lg = l >> 4;         // k-chunk group 0..3

    const float* cb = codebook + (size_t)m * PK * PD;
    const float* wm = wq + (size_t)m * PD * PD;

    // A fragments: 4 K-steps, 8 contiguous fp32 along d each.
    const int k = ktile + wv * 16 + lr;
    const float* asrc = cb + (size_t)k * PD + lg * 8;
    bf16x8 afrag[4];
#pragma unroll
    for (int kk = 0; kk < 4; ++kk) {
        afrag[kk] = loadcvt8(asrc + kk * 32);
    }

#pragma unroll
    for (int cs = 0; cs < 8; ++cs) {
        const int c = cs * 16 + lr;
        bf16x8 bfrag[4];
        const float* src = wm + (size_t)c * PD + lg * 8;
#pragma unroll
        for (int kk = 0; kk < 4; ++kk) {
            bfrag[kk] = loadcvt8(src + kk * 32);
        }
        const float bias = bq[m * PD + c];
        f32x4 acc = {0.f, 0.f, 0.f, 0.f};
#pragma unroll
        for (int kk = 0; kk < 4; ++kk) {
            acc = __builtin_amdgcn_mfma_f32_16x16x32_bf16(
                    afrag[kk], bfrag[kk], acc, 0, 0, 0);
        }
        // C/D layout: col = lane&15, row = (lane>>4)*4 + j   [m89 verified]
        const int kb = ktile + wv * 16 + lg * 4;
        unsigned short* dst = table + ((size_t)(m * PK + kb)) * PD + cs * 16 + lr;
#pragma unroll
        for (int j = 0; j < 4; ++j) {
            dst[(size_t)j * PD] = f2bf_rne(acc[j] + bias);
        }
    }
}

// ---------------------------------------------------------------------------
// Kernel 2: out[n, m*128+c, h, w] = table[m, codes[n,h,w,m], c]
// Restructured for fill-like stores: block = (m, n, cg of 32 c, hg of 16 h).
// Lane handles 4 consecutive w -> 4 row gathers of 64B, stores dwordx4.
// One wave store instr = 4h x 64w = 1 KB contiguous; block writes 4 KB
// contiguous per channel. m = b&7 keeps each XCD on its 1 MB table slice.
// Grid: 1024 blocks x 256 threads.
// ---------------------------------------------------------------------------
__global__ __launch_bounds__(256) void gather_scatter(
        const int* __restrict__ codes,
        const unsigned short* __restrict__ table,
        float* __restrict__ out) {
    const int b = blockIdx.x;
    const int m  = b & 7;
    const int r  = b >> 3;
    const int hg = r & 3;          // low bits: consecutive blocks -> adjacent h
    const int cg = (r >> 2) & 3;
    const int n  = r >> 4;
    const int tid = threadIdx.x;
    const int wv = tid >> 6;
    const int l  = tid & 63;

    const int h  = hg * 16 + wv * 4 + (l >> 4);
    const int w0 = (l & 15) * 4;
    const int c0 = cg * 32;

    // 4 codes for w0..w0+3
    const int* cbase = codes + ((size_t)(n * PH + h) * PW + w0) * PM + m;
    int code0 = cbase[0 * PM];
    int code1 = cbase[1 * PM];
    int code2 = cbase[2 * PM];
    int code3 = cbase[3 * PM];

    // Gather 64 B (32 c) per position: 4 chunks of 16 B each.
    const unsigned short* trow0 = table + ((size_t)m * PK + code0) * PD + c0;
    const unsigned short* trow1 = table + ((size_t)m * PK + code1) * PD + c0;
    const unsigned short* trow2 = table + ((size_t)m * PK + code2) * PD + c0;
    const unsigned short* trow3 = table + ((size_t)m * PK + code3) * PD + c0;

    short8v raw0[4], raw1[4], raw2[4], raw3[4];
#pragma unroll
    for (int ci = 0; ci < 4; ++ci) {
        raw0[ci] = *(const short8v*)(trow0 + ci * 8);
        raw1[ci] = *(const short8v*)(trow1 + ci * 8);
        raw2[ci] = *(const short8v*)(trow2 + ci * 8);
        raw3[ci] = *(const short8v*)(trow3 + ci * 8);
    }

    float* ob = out + (((size_t)n * (PM * PD) + m * PD + c0) * PH + h) * PW + w0;
#pragma unroll
    for (int ci = 0; ci < 4; ++ci) {
#pragma unroll
        for (int j = 0; j < 8; ++j) {
            const int c = ci * 8 + j;
            f32x4 v;
            v[0] = bf2f((unsigned short)raw0[ci][j]);
            v[1] = bf2f((unsigned short)raw1[ci][j]);
            v[2] = bf2f((unsigned short)raw2[ci][j]);
            v[3] = bf2f((unsigned short)raw3[ci][j]);
            __builtin_nontemporal_store(v, (f32x4*)(ob + (size_t)c * (PH * PW)));
        }
    }
}

// ---------------------------------------------------------------------------
// Fallback (only if ws_size < table size): fused direct compute, fp32.
// ---------------------------------------------------------------------------
__global__ __launch_bounds__(256) void fused_direct(
        const int* __restrict__ codes,
        const float* __restrict__ codebook,
        const float* __restrict__ wq,
        const float* __restrict__ bq,
        float* __restrict__ out) {
    __shared__ float rows[PW][133];
    const int b = blockIdx.x;
    const int m = b & 7;
    const int rest = b >> 3;
    const int n = rest >> 6;
    const int h = rest & 63;
    const int tid = threadIdx.x;

    for (int idx = tid; idx < PW * 32; idx += 256) {
        const int r = idx >> 5;
        const int e = (idx & 31) * 4;
        const int code = codes[((n * PH + h) * PW + r) * PM + m];
        const float* src = codebook + ((size_t)m * PK + code) * PD + e;
#pragma unroll
        for (int j = 0; j < 4; ++j) rows[r][e + j] = src[j];
    }
    __syncthreads();

    const int w = tid & 63;
    const int cb0 = (tid >> 6) * 32;
    float* ob = out + (((size_t)n * (PM * PD) + m * PD + cb0) * PH + h) * PW + w;
    for (int ci = 0; ci < 32; ++ci) {
        const int c = cb0 + ci;
        const float* wr = wq + ((size_t)m * PD + c) * PD;
        float acc = bq[m * PD + c];
#pragma unroll 4
        for (int d = 0; d < PD; ++d) acc += rows[w][d] * wr[d];
        ob[(size_t)ci * (PH * PW)] = acc;
    }
}

extern "C" void kernel_launch(void* const* d_in, const int* in_sizes, int n_in,
                              void* d_out, int out_size, void* d_ws, size_t ws_size,
                              hipStream_t stream) {
    const int*   codes    = (const int*)  d_in[0];
    const float* codebook = (const float*)d_in[1];
    const float* wq       = (const float*)d_in[2];
    const float* bq       = (const float*)d_in[3];
    float* out = (float*)d_out;

    const size_t table_bytes = (size_t)PM * PK * PD * sizeof(unsigned short); // 8 MB
    if (ws_size >= table_bytes) {
        unsigned short* table = (unsigned short*)d_ws;
        build_table<<<dim3(512), dim3(256), 0, stream>>>(codebook, wq, bq, table);
        gather_scatter<<<dim3(1024), dim3(256), 0, stream>>>(codes, table, out);
    } else {
        fused_direct<<<dim3(PM * PN * PH), dim3(256), 0, stream>>>(codes, codebook, wq, bq, out);
    }
}

// Round 3
// 43.582 us; speedup vs baseline: 1.2328x; 1.2328x over previous
//
#include <hip/hip_runtime.h>
#include <hip/hip_bf16.h>

// Problem constants
#define PM 8        // groups
#define PK 4096     // codebook entries per group
#define PD 128      // dim
#define PN 8
#define PH 64
#define PW 64

typedef __attribute__((ext_vector_type(8))) short bf16x8;
typedef __attribute__((ext_vector_type(4))) float f32x4;
typedef __attribute__((ext_vector_type(2))) float f32x2;
typedef __attribute__((ext_vector_type(8))) short short8v;

__device__ inline unsigned short f2bf_rne(float f) {
    unsigned int u = __float_as_uint(f);
    unsigned int r = (u + 0x7FFFu + ((u >> 16) & 1u)) >> 16;
    return (unsigned short)r;
}
__device__ inline float bf2f(unsigned short s) {
    return __uint_as_float(((unsigned int)s) << 16);
}

__device__ inline bf16x8 loadcvt8(const float* __restrict__ p) {
    f32x4 x0 = *(const f32x4*)p;
    f32x4 x1 = *(const f32x4*)(p + 4);
    bf16x8 r;
#pragma unroll
    for (int j = 0; j < 4; ++j) {
        r[j]     = (short)f2bf_rne(x0[j]);
        r[j + 4] = (short)f2bf_rne(x1[j]);
    }
    return r;
}

// ---------------------------------------------------------------------------
// Kernel 1: table[m,k,c] = sum_d codebook[m,k,d]*wq[m,c,d] + bq[m,c]  (bf16)
// Round-1 shape (wave = 32 k-rows, 2 k-subtiles amortize B-frags), but grid
// split over c-halves instead of k: 512 blocks = m(8) x ktile(32) x chalf(2).
// Per-block B-conversion halves, total unchanged; 2 blocks/CU occupancy.
// ---------------------------------------------------------------------------
__global__ __launch_bounds__(256) void build_table(
        const float* __restrict__ codebook,
        const float* __restrict__ wq,
        const float* __restrict__ bq,
        unsigned short* __restrict__ table) {
    const int b = blockIdx.x;
    const int m = b & 7;
    const int r = b >> 3;
    const int ktile = (r & 31) * 128;
    const int cshalf = r >> 5;          // 0 or 1 -> cs in [cshalf*4, cshalf*4+4)
    const int tid = threadIdx.x;
    const int wv = tid >> 6;            // wave 0..3
    const int l  = tid & 63;
    const int lr = l & 15;
    const int lg = l >> 4;

    const float* cb = codebook + (size_t)m * PK * PD;
    const float* wm = wq + (size_t)m * PD * PD;

    bf16x8 afrag[2][4];
#pragma unroll
    for (int ks = 0; ks < 2; ++ks) {
        const int k = ktile + wv * 32 + ks * 16 + lr;
        const float* src = cb + (size_t)k * PD + lg * 8;
#pragma unroll
        for (int kk = 0; kk < 4; ++kk) {
            afrag[ks][kk] = loadcvt8(src + kk * 32);
        }
    }

#pragma unroll
    for (int i = 0; i < 4; ++i) {
        const int cs = cshalf * 4 + i;
        const int c = cs * 16 + lr;
        bf16x8 bfrag[4];
        const float* src = wm + (size_t)c * PD + lg * 8;
#pragma unroll
        for (int kk = 0; kk < 4; ++kk) {
            bfrag[kk] = loadcvt8(src + kk * 32);
        }
        const float bias = bq[m * PD + c];
#pragma unroll
        for (int ks = 0; ks < 2; ++ks) {
            f32x4 acc = {0.f, 0.f, 0.f, 0.f};
#pragma unroll
            for (int kk = 0; kk < 4; ++kk) {
                acc = __builtin_amdgcn_mfma_f32_16x16x32_bf16(
                        afrag[ks][kk], bfrag[kk], acc, 0, 0, 0);
            }
            // C/D layout: col = lane&15, row = (lane>>4)*4 + j   [m89 verified]
            const int kb = ktile + wv * 32 + ks * 16 + lg * 4;
            unsigned short* dst = table + ((size_t)(m * PK + kb)) * PD + cs * 16 + lr;
#pragma unroll
            for (int j = 0; j < 4; ++j) {
                dst[(size_t)j * PD] = f2bf_rne(acc[j] + bias);
            }
        }
    }
}

// ---------------------------------------------------------------------------
// Kernel 2: out[n, m*128+c, h, w] = table[m, codes[n,h,w,m], c]
// Controlled store-width experiment vs round-1:
//   lane = (2 consecutive w) x (2 h within wave); wave covers 32 w-pairs x 2 h.
//   Store instr = f32x2/lane = 512 B contiguous (two adjacent 256 B h-rows).
//   Gather unchanged: per code 64 B row-quarter via 4x dwordx4.
// Block = (m, n, cg of 32 c, hg of 8 h); grid 2048 x 256 thr = 8192 waves.
// m = b&7 keeps each XCD on its 1 MB table slice.
// ---------------------------------------------------------------------------
__global__ __launch_bounds__(256, 4) void gather_scatter(
        const int* __restrict__ codes,
        const unsigned short* __restrict__ table,
        float* __restrict__ out) {
    const int b = blockIdx.x;
    const int m  = b & 7;
    const int r  = b >> 3;           // 0..255
    const int hg = r & 7;            // low bits: consecutive blocks -> adjacent h
    const int cg = (r >> 3) & 3;
    const int n  = r >> 5;
    const int tid = threadIdx.x;
    const int wv = tid >> 6;
    const int l  = tid & 63;

    const int hh = l >> 5;                  // 0..1
    const int h  = hg * 8 + wv * 2 + hh;    // 0..63
    const int w0 = (l & 31) * 2;            // 0,2,..,62
    const int c0 = cg * 32;

    // 2 codes for (h, w0) and (h, w0+1)
    const int* cbase = codes + ((size_t)(n * PH + h) * PW + w0) * PM + m;
    const int code0 = cbase[0];
    const int code1 = cbase[PM];

    const unsigned short* trow0 = table + ((size_t)m * PK + code0) * PD + c0;
    const unsigned short* trow1 = table + ((size_t)m * PK + code1) * PD + c0;

    short8v raw0[4], raw1[4];
#pragma unroll
    for (int ci = 0; ci < 4; ++ci) {
        raw0[ci] = *(const short8v*)(trow0 + ci * 8);
        raw1[ci] = *(const short8v*)(trow1 + ci * 8);
    }

    float* ob = out + (((size_t)n * (PM * PD) + m * PD + c0) * PH + h) * PW + w0;
#pragma unroll
    for (int ci = 0; ci < 4; ++ci) {
#pragma unroll
        for (int j = 0; j < 8; ++j) {
            const int c = ci * 8 + j;
            f32x2 v;
            v[0] = bf2f((unsigned short)raw0[ci][j]);
            v[1] = bf2f((unsigned short)raw1[ci][j]);
            __builtin_nontemporal_store(v, (f32x2*)(ob + (size_t)c * (PH * PW)));
        }
    }
}

// ---------------------------------------------------------------------------
// Fallback (only if ws_size < table size): fused direct compute, fp32.
// ---------------------------------------------------------------------------
__global__ __launch_bounds__(256) void fused_direct(
        const int* __restrict__ codes,
        const float* __restrict__ codebook,
        const float* __restrict__ wq,
        const float* __restrict__ bq,
        float* __restrict__ out) {
    __shared__ float rows[PW][133];
    const int b = blockIdx.x;
    const int m = b & 7;
    const int rest = b >> 3;
    const int n = rest >> 6;
    const int h = rest & 63;
    const int tid = threadIdx.x;

    for (int idx = tid; idx < PW * 32; idx += 256) {
        const int r = idx >> 5;
        const int e = (idx & 31) * 4;
        const int code = codes[((n * PH + h) * PW + r) * PM + m];
        const float* src = codebook + ((size_t)m * PK + code) * PD + e;
#pragma unroll
        for (int j = 0; j < 4; ++j) rows[r][e + j] = src[j];
    }
    __syncthreads();

    const int w = tid & 63;
    const int cb0 = (tid >> 6) * 32;
    float* ob = out + (((size_t)n * (PM * PD) + m * PD + cb0) * PH + h) * PW + w;
    for (int ci = 0; ci < 32; ++ci) {
        const int c = cb0 + ci;
        const float* wr = wq + ((size_t)m * PD + c) * PD;
        float acc = bq[m * PD + c];
#pragma unroll 4
        for (int d = 0; d < PD; ++d) acc += rows[w][d] * wr[d];
        ob[(size_t)ci * (PH * PW)] = acc;
    }
}

extern "C" void kernel_launch(void* const* d_in, const int* in_sizes, int n_in,
                              void* d_out, int out_size, void* d_ws, size_t ws_size,
                              hipStream_t stream) {
    const int*   codes    = (const int*)  d_in[0];
    const float* codebook = (const float*)d_in[1];
    const float* wq       = (const float*)d_in[2];
    const float* bq       = (const float*)d_in[3];
    float* out = (float*)d_out;

    const size_t table_bytes = (size_t)PM * PK * PD * sizeof(unsigned short); // 8 MB
    if (ws_size >= table_bytes) {
        unsigned short* table = (unsigned short*)d_ws;
        build_table<<<dim3(512), dim3(256), 0, stream>>>(codebook, wq, bq, table);
        gather_scatter<<<dim3(2048), dim3(256), 0, stream>>>(codes, table, out);
    } else {
        fused_direct<<<dim3(PM * PN * PH), dim3(256), 0, stream>>>(codes, codebook, wq, bq, out);
    }
}